// Round 3
// baseline (1757.403 us; speedup 1.0000x reference)
//
#include <hip/hip_runtime.h>
#include <hip/hip_bf16.h>

#define BT 16384
#define FDIM 768
#define HDIM 3072

typedef __attribute__((ext_vector_type(8))) short bf16x8;
typedef __attribute__((ext_vector_type(4))) float f32x4;
typedef __attribute__((ext_vector_type(4))) int i32x4;
typedef __attribute__((ext_vector_type(2))) float f32x2;

__device__ inline float b2f(unsigned short u) {
  union { unsigned int i; float f; } x; x.i = ((unsigned int)u) << 16; return x.f;
}

// async global->LDS, 16B per lane: LDS dest = uniform base + lane*16
#define GLOAD16(gptr, lptr)                                                    \
  __builtin_amdgcn_global_load_lds(                                            \
      (const __attribute__((address_space(1))) void*)(gptr),                   \
      (__attribute__((address_space(3))) void*)(lptr), 16, 0, 0)

// ---------- five 768x768 weight transposes (f32 [K,N] -> bf16 [N,K]) in one launch
__global__ void wconv5_kernel(const float* s0, const float* s1, const float* s2,
                              const float* s3, const float* s4,
                              __hip_bfloat16* d0, __hip_bfloat16* d1, __hip_bfloat16* d2,
                              __hip_bfloat16* d3, __hip_bfloat16* d4) {
  const float* in; __hip_bfloat16* out;
  switch (blockIdx.z) {
    case 0: in = s0; out = d0; break;
    case 1: in = s1; out = d1; break;
    case 2: in = s2; out = d2; break;
    case 3: in = s3; out = d3; break;
    default: in = s4; out = d4; break;
  }
  __shared__ float tile[32][33];
  int kb = blockIdx.x * 32, nb = blockIdx.y * 32;
  int tx = threadIdx.x & 31, ty = threadIdx.x >> 5;
#pragma unroll
  for (int i = 0; i < 4; ++i) {
    int k = ty + i * 8;
    tile[k][tx] = in[(size_t)(kb + k) * 768 + nb + tx];
  }
  __syncthreads();
#pragma unroll
  for (int i = 0; i < 4; ++i) {
    int n = ty + i * 8;
    out[(size_t)(nb + n) * 768 + kb + tx] = __float2bfloat16(tile[tx][n]);
  }
}

__global__ void wconv_kernel(const float* __restrict__ in, __hip_bfloat16* __restrict__ out,
                             int K, int N) {
  __shared__ float tile[32][33];
  int kb = blockIdx.x * 32, nb = blockIdx.y * 32;
  int tx = threadIdx.x & 31, ty = threadIdx.x >> 5;
#pragma unroll
  for (int i = 0; i < 4; ++i) {
    int k = ty + i * 8;
    tile[k][tx] = in[(size_t)(kb + k) * N + nb + tx];
  }
  __syncthreads();
#pragma unroll
  for (int i = 0; i < 4; ++i) {
    int n = ty + i * 8;
    out[(size_t)(nb + n) * K + kb + tx] = __float2bfloat16(tile[tx][n]);
  }
}

// ---------- fuse_W [768,1536] -> WdT3 [768 n][2304 k] bf16 3-split of (W[:,2n]-W[:,2n+1])
__global__ void wdsplit_kernel(const float* __restrict__ W, __hip_bfloat16* __restrict__ out) {
  __shared__ float tile[32][33];
  int kb = blockIdx.x * 32, nb = blockIdx.y * 32;
  int tx = threadIdx.x & 31, ty = threadIdx.x >> 5;
#pragma unroll
  for (int i = 0; i < 4; ++i) {
    int k = ty + i * 8;
    f32x2 p = ((const f32x2*)(W + (size_t)(kb + k) * 1536))[nb + tx];
    tile[k][tx] = p.x - p.y;
  }
  __syncthreads();
#pragma unroll
  for (int i = 0; i < 4; ++i) {
    int n = ty + i * 8;
    float d = tile[tx][n];
    __hip_bfloat16 h1 = __float2bfloat16(d);
    float r1 = d - __bfloat162float(h1);
    __hip_bfloat16 h2 = __float2bfloat16(r1);
    float r2 = r1 - __bfloat162float(h2);
    __hip_bfloat16 h3 = __float2bfloat16(r2);
    size_t base = (size_t)(nb + n) * 2304 + kb + tx;
    out[base] = h1; out[base + 768] = h2; out[base + 1536] = h3;
  }
}

// ---------- feat -> FS [BT, 2304] bf16 3-split, 4 elems/thread
__global__ void featsplit_kernel(const float* __restrict__ fv, const float* __restrict__ fi,
                                 __hip_bfloat16* __restrict__ FS) {
  int idx4 = blockIdx.x * 256 + threadIdx.x;  // BT*192
  int m = idx4 / 192, q = idx4 - m * 192;
  int c0 = q * 4;
  f32x4 f;
  if (c0 < 512) f = *(const f32x4*)(fv + (size_t)m * 512 + c0);
  else          f = *(const f32x4*)(fi + (size_t)m * 256 + (c0 - 512));
  unsigned short h1[4], h2[4], h3[4];
#pragma unroll
  for (int j = 0; j < 4; ++j) {
    float x = f[j];
    __hip_bfloat16 a = __float2bfloat16(x);
    float r1 = x - __bfloat162float(a);
    __hip_bfloat16 b = __float2bfloat16(r1);
    float r2 = r1 - __bfloat162float(b);
    __hip_bfloat16 c = __float2bfloat16(r2);
    h1[j] = *(unsigned short*)&a; h2[j] = *(unsigned short*)&b; h3[j] = *(unsigned short*)&c;
  }
  size_t base = (size_t)m * 2304 + c0;
  *(ushort4*)((unsigned short*)FS + base)        = make_ushort4(h1[0], h1[1], h1[2], h1[3]);
  *(ushort4*)((unsigned short*)FS + base + 768)  = make_ushort4(h2[0], h2[1], h2[2], h2[3]);
  *(ushort4*)((unsigned short*)FS + base + 1536) = make_ushort4(h3[0], h3[1], h3[2], h3[3]);
}

// ---------- fused LN + time-mix: 5 waves, 4 tokens/block + halo
__global__ void lnmix3_kernel(const float* __restrict__ X, const float* __restrict__ g,
                              const float* __restrict__ b, const float* __restrict__ mk,
                              const float* __restrict__ mv, const float* __restrict__ mr,
                              __hip_bfloat16* __restrict__ AK, __hip_bfloat16* __restrict__ AV,
                              __hip_bfloat16* __restrict__ AR) {
  __shared__ float xn[5][768];
  int tok0 = blockIdx.x * 4;
  int w = threadIdx.x >> 6, lane = threadIdx.x & 63;
  int t = tok0 + w - 1;
  if (t >= 0) {
    const float* row = X + (size_t)t * 768;
    float vv[12]; float s = 0.f, s2 = 0.f;
#pragma unroll
    for (int i = 0; i < 12; ++i) { float x = row[lane + i * 64]; vv[i] = x; s += x; s2 += x * x; }
#pragma unroll
    for (int o = 32; o; o >>= 1) { s += __shfl_xor(s, o); s2 += __shfl_xor(s2, o); }
    float m = s * (1.0f / 768.0f);
    float var = s2 * (1.0f / 768.0f) - m * m;
    float inv = 1.0f / sqrtf(var + 1e-5f);
#pragma unroll
    for (int i = 0; i < 12; ++i) { int c = lane + i * 64; xn[w][c] = (vv[i] - m) * inv * g[c] + b[c]; }
  }
  __syncthreads();
  if (w >= 1) {
    int tt = tok0 + (w - 1);
    bool first = (tt & 511) == 0;
    size_t base = (size_t)tt * 768;
#pragma unroll
    for (int i = 0; i < 12; ++i) {
      int c = lane + i * 64;
      float a = xn[w][c];
      float sft = first ? 0.0f : xn[w - 1][c];
      float k = mk[c], v = mv[c], r = mr[c];
      AK[base + c] = __float2bfloat16(a * k + sft * (1.0f - k));
      AV[base + c] = __float2bfloat16(a * v + sft * (1.0f - v));
      AR[base + c] = __float2bfloat16(a * r + sft * (1.0f - r));
    }
  }
}

__global__ void lnmix2_kernel(const float* __restrict__ X, const float* __restrict__ g,
                              const float* __restrict__ b, const float* __restrict__ mk,
                              const float* __restrict__ mr,
                              __hip_bfloat16* __restrict__ AK, __hip_bfloat16* __restrict__ AR) {
  __shared__ float xn[5][768];
  int tok0 = blockIdx.x * 4;
  int w = threadIdx.x >> 6, lane = threadIdx.x & 63;
  int t = tok0 + w - 1;
  if (t >= 0) {
    const float* row = X + (size_t)t * 768;
    float vv[12]; float s = 0.f, s2 = 0.f;
#pragma unroll
    for (int i = 0; i < 12; ++i) { float x = row[lane + i * 64]; vv[i] = x; s += x; s2 += x * x; }
#pragma unroll
    for (int o = 32; o; o >>= 1) { s += __shfl_xor(s, o); s2 += __shfl_xor(s2, o); }
    float m = s * (1.0f / 768.0f);
    float var = s2 * (1.0f / 768.0f) - m * m;
    float inv = 1.0f / sqrtf(var + 1e-5f);
#pragma unroll
    for (int i = 0; i < 12; ++i) { int c = lane + i * 64; xn[w][c] = (vv[i] - m) * inv * g[c] + b[c]; }
  }
  __syncthreads();
  if (w >= 1) {
    int tt = tok0 + (w - 1);
    bool first = (tt & 511) == 0;
    size_t base = (size_t)tt * 768;
#pragma unroll
    for (int i = 0; i < 12; ++i) {
      int c = lane + i * 64;
      float a = xn[w][c];
      float sft = first ? 0.0f : xn[w - 1][c];
      float k = mk[c], r = mr[c];
      AK[base + c] = __float2bfloat16(a * k + sft * (1.0f - k));
      AR[base + c] = __float2bfloat16(a * r + sft * (1.0f - r));
    }
  }
}

// ---------- WKV scan: one thread per (b,c), group-of-4 software pipeline
__global__ void wkv_kernel(const float* __restrict__ K, const float* __restrict__ V,
                           const float* __restrict__ RP, const float* __restrict__ td,
                           const float* __restrict__ tfirst, __hip_bfloat16* __restrict__ RA) {
  int idx = blockIdx.x * 256 + threadIdx.x;  // 32*768
  int b = idx / 768, c = idx - b * 768;
  float decay = -__expf(td[c]);
  float u = tfirst[c];
  float aa = 0.f, bb = 0.f, pp = -1e38f;
  size_t o = (size_t)b * 512 * 768 + c;
  float ck[4], cv[4], cr[4], nk[4], nv[4], nr[4];
#pragma unroll
  for (int j = 0; j < 4; ++j) { size_t oj = o + (size_t)j * 768; ck[j] = K[oj]; cv[j] = V[oj]; cr[j] = RP[oj]; }
  size_t ob = o;
  for (int g = 0; g < 128; ++g) {
    size_t onext = (g == 127) ? o : ob + 3072;
#pragma unroll
    for (int j = 0; j < 4; ++j) {
      size_t oj = onext + (size_t)j * 768;
      nk[j] = K[oj]; nv[j] = V[oj]; nr[j] = RP[oj];
    }
#pragma unroll
    for (int j = 0; j < 4; ++j) {
      float kt = ck[j], vt = cv[j];
      float ww = u + kt;
      float p = fmaxf(pp, ww);
      float e1 = __expf(pp - p), e2 = __expf(ww - p);
      float wkv = (e1 * aa + e2 * vt) / (e1 * bb + e2);
      float ww2 = pp + decay;
      float p2 = fmaxf(ww2, kt);
      float f1 = __expf(ww2 - p2), f2 = __expf(kt - p2);
      aa = f1 * aa + f2 * vt; bb = f1 * bb + f2; pp = p2;
      float r = 1.0f / (1.0f + __expf(-cr[j]));
      RA[ob + (size_t)j * 768] = __float2bfloat16(r * wkv);
    }
#pragma unroll
    for (int j = 0; j < 4; ++j) { ck[j] = nk[j]; cv[j] = nv[j]; cr[j] = nr[j]; }
    ob += 3072;
  }
}

// ---------- regressor stage 2
__global__ void reg2_kernel(const __hip_bfloat16* __restrict__ Hb, const float* __restrict__ W2,
                            const float* __restrict__ b2, float* __restrict__ out) {
  __shared__ float w[768];
  for (int i = threadIdx.x; i < 768; i += 256) w[i] = W2[i];
  __syncthreads();
  int m = blockIdx.x * 256 + threadIdx.x;
  float acc[6];
#pragma unroll
  for (int j = 0; j < 6; ++j) acc[j] = b2[j];
  const bf16x8* hr8 = (const bf16x8*)(Hb + (size_t)m * 128);
#pragma unroll
  for (int h8 = 0; h8 < 16; ++h8) {
    bf16x8 pk = hr8[h8];
#pragma unroll
    for (int e = 0; e < 8; ++e) {
      float hv = b2f((unsigned short)pk[e]);
      int h = h8 * 8 + e;
#pragma unroll
      for (int j = 0; j < 6; ++j) acc[j] += hv * w[h * 6 + j];
    }
  }
#pragma unroll
  for (int j = 0; j < 6; ++j) out[(size_t)m * 6 + j] = acc[j];
}

// ---------- MFMA GEMM: A [M,Kphys] bf16 rm, Bt [N,Kphys] bf16 rm. 128x128 tile, BK=64.
// 2-phase prefetch double-buffer (T3-minimum): issue global_load_lds for tile t+1
// BEFORE computing tile t; single barrier per K-step. Linear LDS dest +
// inverse-XOR pre-swizzled global source + XOR-swizzled ds_read (rule #21).
// 1D grid + chunked XCD swizzle (T1/m204), y-fast so one A-panel's column
// blocks are contiguous on one XCD (A-panel L2-resident).
enum { EP_NONE = 0, EP_GATE, EP_RESID, EP_RELUSQ, EP_SIGRESID, EP_LEAKY };

template<int EP, bool SPLIT6>
__global__ void gemm_bt(const __hip_bfloat16* __restrict__ A, const __hip_bfloat16* __restrict__ Bt,
                        int N, int Kphys, int Klog, int ny,
                        size_t aZ, size_t bZ, size_t oZ,
                        float* __restrict__ outF, __hip_bfloat16* __restrict__ outH,
                        const float* __restrict__ x0, const float* __restrict__ x1,
                        const float* __restrict__ x2, const float* __restrict__ x3) {
  __shared__ __align__(16) unsigned short sA0[8192];
  __shared__ __align__(16) unsigned short sB0[8192];
  __shared__ __align__(16) unsigned short sA1[8192];
  __shared__ __align__(16) unsigned short sB1[8192];
  const int tid = threadIdx.x;
  const int lane = tid & 63;
  const int wid = tid >> 6;

  // chunked XCD swizzle: hardware block w -> logical tile wp; nwg % 8 == 0.
  const int w = blockIdx.x;
  const int nwg = gridDim.x;
  const int wp = (w & 7) * (nwg >> 3) + (w >> 3);
  const int bx = wp / ny, by = wp - bx * ny;
  const int tm = bx * 128, tn = by * 128;

  const int wr = (wid >> 1) * 64, wc = (wid & 1) * 64;
  const int r16 = lane & 15, kg = lane >> 4;
  const int z = blockIdx.z;
  A += (size_t)z * aZ; Bt += (size_t)z * bZ;

  f32x4 acc[4][4];
  f32x4 zero = {0.f, 0.f, 0.f, 0.f};
#pragma unroll
  for (int i = 0; i < 4; ++i)
#pragma unroll
    for (int j = 0; j < 4; ++j) acc[i][j] = zero;

  // staging: 16 chunks of 1KB (8 rows x 64 k each); wave w issues chunks 4w..4w+3.
  size_t gA[4], gB[4];
  int ldsOff[4];
#pragma unroll
  for (int i = 0; i < 4; ++i) {
    int c = (wid << 2) | i;
    int row = (c << 3) | (lane >> 3);
    int swz = ((lane & 7) ^ (row & 7)) << 3;  // element offset (inverse XOR pre-swizzle)
    gA[i] = (size_t)(tm + row) * Kphys + swz;
    gB[i] = (size_t)(tn + row) * Kphys + swz;
    ldsOff[i] = c << 9;  // elements (1KB per chunk)
  }
  const int ca0 = ((kg ^ (r16 & 7)) << 4);
  const int ca1 = (((4 | kg) ^ (r16 & 7)) << 4);
  const int arow = (wr + r16) * 128;
  const int brow = (wc + r16) * 128;

  auto STAGE = [&](unsigned short* dA, unsigned short* dB, int st) {
    int k0 = st * 64;
    int kA, kB2;
    if (SPLIT6) {
      static constexpr int mapA[6] = {0, 0, 0, 1, 1, 2};
      static constexpr int mapB[6] = {0, 1, 2, 0, 1, 0};
      int s = k0 / 768; int kr = k0 - s * 768;
      kA = mapA[s] * 768 + kr; kB2 = mapB[s] * 768 + kr;
    } else { kA = k0; kB2 = k0; }
#pragma unroll
    for (int i = 0; i < 4; ++i) GLOAD16(A + gA[i] + kA, dA + ldsOff[i]);
#pragma unroll
    for (int i = 0; i < 4; ++i) GLOAD16(Bt + gB[i] + kB2, dB + ldsOff[i]);
  };

  auto COMPUTE = [&](const unsigned short* cA, const unsigned short* cB) {
#pragma unroll
    for (int ks = 0; ks < 2; ++ks) {
      const int ca = ks ? ca1 : ca0;
      bf16x8 af[4], bfv[4];
#pragma unroll
      for (int f = 0; f < 4; ++f) {
        af[f]  = *(const bf16x8*)((const char*)cA + arow + f * 2048 + ca);
        bfv[f] = *(const bf16x8*)((const char*)cB + brow + f * 2048 + ca);
      }
#pragma unroll
      for (int fm = 0; fm < 4; ++fm)
#pragma unroll
        for (int fn = 0; fn < 4; ++fn)
          acc[fm][fn] = __builtin_amdgcn_mfma_f32_16x16x32_bf16(af[fm], bfv[fn], acc[fm][fn], 0, 0, 0);
    }
  };

  const int nsteps = Klog / 64;  // all call sites: even, >= 2
  STAGE(sA0, sB0, 0);
  __syncthreads();
  for (int st = 0; st + 2 <= nsteps; st += 2) {
    STAGE(sA1, sB1, st + 1);
    COMPUTE(sA0, sB0);
    __syncthreads();
    if (st + 2 < nsteps) STAGE(sA0, sB0, st + 2);
    COMPUTE(sA1, sB1);
    __syncthreads();
  }

  // epilogue: C[row][col], col = lane&15, row = (lane>>4)*4 + j
  const int er0 = tm + wr + (lane >> 4) * 4;
  const int ec0 = tn + wc + (lane & 15);
#pragma unroll
  for (int fm = 0; fm < 4; ++fm) {
#pragma unroll
    for (int fn = 0; fn < 4; ++fn) {
#pragma unroll
      for (int j = 0; j < 4; ++j) {
        int row = er0 + fm * 16 + j;
        int col = ec0 + fn * 16;
        float v = acc[fm][fn][j];
        size_t o = (size_t)row * N + col;
        if (EP == EP_NONE) {
          outF[(size_t)z * oZ + o] = v;
        } else if (EP == EP_RESID) {
          outF[o] += v;
        } else if (EP == EP_GATE) {
          size_t gi = ((size_t)row * 768 + col) * 2;
          float gd = x0[gi] - x0[gi + 1];
          float bd = x3[2 * col] - x3[2 * col + 1];
          float s = v + bd + gd;
          float feat = (col < 512) ? x1[(size_t)row * 512 + col]
                                   : x2[(size_t)row * 256 + col - 512];
          outF[o] = (s >= 0.0f) ? feat : 0.0f;
        } else if (EP == EP_RELUSQ) {
          float r = v > 0.f ? v : 0.f;
          outH[o] = __float2bfloat16(r * r);
        } else if (EP == EP_SIGRESID) {
          float sg = 1.0f / (1.0f + __expf(-x0[o]));
          float xv = x1[o] + sg * v;
          outH[o] = __float2bfloat16(xv);
        } else if (EP == EP_LEAKY) {
          float h = v + x0[col];
          h = h > 0.f ? h : 0.1f * h;
          outH[o] = __float2bfloat16(h);
        }
      }
    }
  }
}

extern "C" void kernel_launch(void* const* d_in, const int* in_sizes, int n_in,
                              void* d_out, int out_size, void* d_ws, size_t ws_size,
                              hipStream_t stream) {
  const float* fv     = (const float*)d_in[0];
  const float* fi     = (const float*)d_in[1];
  const float* fuse_W = (const float*)d_in[2];
  const float* fuse_b = (const float*)d_in[3];
  const float* gumbel = (const float*)d_in[4];
  const float* ln1_g  = (const float*)d_in[5];
  const float* ln1_b  = (const float*)d_in[6];
  const float* mix_k  = (const float*)d_in[7];
  const float* mix_v  = (const float*)d_in[8];
  const float* mix_r  = (const float*)d_in[9];
  const float* td     = (const float*)d_in[10];
  const float* tfirst = (const float*)d_in[11];
  const float* Wk     = (const float*)d_in[12];
  const float* Wv     = (const float*)d_in[13];
  const float* Wr     = (const float*)d_in[14];
  const float* Wo     = (const float*)d_in[15];
  const float* ln2_g  = (const float*)d_in[16];
  const float* ln2_b  = (const float*)d_in[17];
  const float* cmk    = (const float*)d_in[18];
  const float* cmr    = (const float*)d_in[19];
  const float* cWk    = (const float*)d_in[20];
  const float* cWv    = (const float*)d_in[21];
  const float* cWr    = (const float*)d_in[22];
  const float* rW1    = (const float*)d_in[23];
  const float* rb1    = (const float*)d_in[24];
  const float* rW2    = (const float*)d_in[25];
  const float* rb2    = (const float*)d_in[26];

  char* ws = (char*)d_ws;
  float* X  = (float*)(ws + 0);
  float* Kb = (float*)(ws + 100663296UL);
  float* RP = (float*)(ws + 201326592UL);
  __hip_bfloat16* AK  = (__hip_bfloat16*)(ws + 251658240UL);
  __hip_bfloat16* AV  = (__hip_bfloat16*)(ws + 276824064UL);
  __hip_bfloat16* AR  = (__hip_bfloat16*)(ws + 301989888UL);
  __hip_bfloat16* RA  = (__hip_bfloat16*)(ws + 327155712UL);
  __hip_bfloat16* Hb  = (__hip_bfloat16*)(ws + 352321536UL);
  __hip_bfloat16* WdT = (__hip_bfloat16*)(ws + 356515840UL);
  __hip_bfloat16* WkT = (__hip_bfloat16*)(ws + 360054784UL);
  __hip_bfloat16* cWkT = (__hip_bfloat16*)(ws + 364773376UL);
  __hip_bfloat16* cWvT = (__hip_bfloat16*)(ws + 369491968UL);
  __hip_bfloat16* cWrT = (__hip_bfloat16*)(ws + 374210560UL);
  __hip_bfloat16* W1T  = (__hip_bfloat16*)(ws + 375390208UL);
  __hip_bfloat16* WvT = (__hip_bfloat16*)(ws + 361234432UL);
  __hip_bfloat16* WrT = (__hip_bfloat16*)(ws + 362414080UL);
  __hip_bfloat16* WoT = (__hip_bfloat16*)(ws + 363593728UL);
  // aliases over dead K/V region:
  __hip_bfloat16* FS = (__hip_bfloat16*)(ws + 100663296UL);  // [BT,2304], dead after gate
  __hip_bfloat16* KK = (__hip_bfloat16*)(ws + 100663296UL);  // [BT,3072], after Kb/Vb dead

  dim3 blk(256);

  // weight converts
  wconv5_kernel<<<dim3(24, 24, 5), blk, 0, stream>>>(Wk, Wv, Wr, Wo, cWr,
                                                     WkT, WvT, WrT, WoT, cWrT);
  wconv_kernel<<<dim3(24, 96), blk, 0, stream>>>(cWk, cWkT, 768, 3072);
  wconv_kernel<<<dim3(96, 24), blk, 0, stream>>>(cWv, cWvT, 3072, 768);
  wconv_kernel<<<dim3(24, 4),  blk, 0, stream>>>(rW1, W1T, 768, 128);
  wdsplit_kernel<<<dim3(24, 24), blk, 0, stream>>>(fuse_W, WdT);

  // fusion gate
  featsplit_kernel<<<12288, blk, 0, stream>>>(fv, fi, FS);
  gemm_bt<EP_GATE, true><<<dim3(768, 1, 1), blk, 0, stream>>>(
      FS, WdT, 768, 2304, 4608, 6, 0, 0, 0, X, nullptr, gumbel, fv, fi, fuse_b);

  // RWKV time-mix
  lnmix3_kernel<<<4096, dim3(320), 0, stream>>>(X, ln1_g, ln1_b, mix_k, mix_v, mix_r, AK, AV, AR);
  gemm_bt<EP_NONE, false><<<dim3(768, 1, 3), blk, 0, stream>>>(
      AK, WkT, 768, 768, 768, 6, 12582912UL, 589824UL, 12582912UL,
      Kb, nullptr, nullptr, nullptr, nullptr, nullptr);
  wkv_kernel<<<96, blk, 0, stream>>>(Kb, Kb + 12582912UL, RP, td, tfirst, RA);
  gemm_bt<EP_RESID, false><<<dim3(768, 1, 1), blk, 0, stream>>>(
      RA, WoT, 768, 768, 768, 6, 0, 0, 0, X, nullptr, nullptr, nullptr, nullptr, nullptr);

  // RWKV channel-mix
  lnmix2_kernel<<<4096, dim3(320), 0, stream>>>(X, ln2_g, ln2_b, cmk, cmr, AK, AR);
  gemm_bt<EP_RELUSQ, false><<<dim3(3072, 1, 1), blk, 0, stream>>>(
      AK, cWkT, 3072, 768, 768, 24, 0, 0, 0, nullptr, KK, nullptr, nullptr, nullptr, nullptr);
  gemm_bt<EP_NONE, false><<<dim3(768, 1, 1), blk, 0, stream>>>(
      AR, cWrT, 768, 768, 768, 6, 0, 0, 0, RP, nullptr, nullptr, nullptr, nullptr, nullptr);
  gemm_bt<EP_SIGRESID, false><<<dim3(768, 1, 1), blk, 0, stream>>>(
      KK, cWvT, 768, 3072, 3072, 6, 0, 0, 0, nullptr, AV, RP, X, nullptr, nullptr);

  // regressor (AV now holds bf16 of final x)
  gemm_bt<EP_LEAKY, false><<<dim3(128, 1, 1), blk, 0, stream>>>(
      AV, W1T, 128, 768, 768, 1, 0, 0, 0, nullptr, Hb, rb1, nullptr, nullptr, nullptr);
  reg2_kernel<<<64, blk, 0, stream>>>(Hb, rW2, rb2, (float*)d_out);
}

// Round 4
// 920.554 us; speedup vs baseline: 1.9091x; 1.9091x over previous
//
#include <hip/hip_runtime.h>
#include <hip/hip_bf16.h>

#define BT 16384
#define FDIM 768
#define HDIM 3072

typedef __attribute__((ext_vector_type(8))) short bf16x8;
typedef __attribute__((ext_vector_type(4))) float f32x4;
typedef __attribute__((ext_vector_type(4))) int i32x4;
typedef __attribute__((ext_vector_type(2))) float f32x2;

__device__ inline float b2f(unsigned short u) {
  union { unsigned int i; float f; } x; x.i = ((unsigned int)u) << 16; return x.f;
}

// async global->LDS, 16B per lane: LDS dest = uniform base + lane*16
#define GLOAD16(gptr, lptr)                                                    \
  __builtin_amdgcn_global_load_lds(                                            \
      (const __attribute__((address_space(1))) void*)(gptr),                   \
      (__attribute__((address_space(3))) void*)(lptr), 16, 0, 0)

// ---------- five 768x768 weight transposes (f32 [K,N] -> bf16 [N,K]) in one launch
__global__ void wconv5_kernel(const float* s0, const float* s1, const float* s2,
                              const float* s3, const float* s4,
                              __hip_bfloat16* d0, __hip_bfloat16* d1, __hip_bfloat16* d2,
                              __hip_bfloat16* d3, __hip_bfloat16* d4) {
  const float* in; __hip_bfloat16* out;
  switch (blockIdx.z) {
    case 0: in = s0; out = d0; break;
    case 1: in = s1; out = d1; break;
    case 2: in = s2; out = d2; break;
    case 3: in = s3; out = d3; break;
    default: in = s4; out = d4; break;
  }
  __shared__ float tile[32][33];
  int kb = blockIdx.x * 32, nb = blockIdx.y * 32;
  int tx = threadIdx.x & 31, ty = threadIdx.x >> 5;
#pragma unroll
  for (int i = 0; i < 4; ++i) {
    int k = ty + i * 8;
    tile[k][tx] = in[(size_t)(kb + k) * 768 + nb + tx];
  }
  __syncthreads();
#pragma unroll
  for (int i = 0; i < 4; ++i) {
    int n = ty + i * 8;
    out[(size_t)(nb + n) * 768 + kb + tx] = __float2bfloat16(tile[tx][n]);
  }
}

__global__ void wconv_kernel(const float* __restrict__ in, __hip_bfloat16* __restrict__ out,
                             int K, int N) {
  __shared__ float tile[32][33];
  int kb = blockIdx.x * 32, nb = blockIdx.y * 32;
  int tx = threadIdx.x & 31, ty = threadIdx.x >> 5;
#pragma unroll
  for (int i = 0; i < 4; ++i) {
    int k = ty + i * 8;
    tile[k][tx] = in[(size_t)(kb + k) * N + nb + tx];
  }
  __syncthreads();
#pragma unroll
  for (int i = 0; i < 4; ++i) {
    int n = ty + i * 8;
    out[(size_t)(nb + n) * K + kb + tx] = __float2bfloat16(tile[tx][n]);
  }
}

// ---------- fuse_W [768,1536] -> WdT3 [768 n][2304 k] bf16 3-split of (W[:,2n]-W[:,2n+1])
__global__ void wdsplit_kernel(const float* __restrict__ W, __hip_bfloat16* __restrict__ out) {
  __shared__ float tile[32][33];
  int kb = blockIdx.x * 32, nb = blockIdx.y * 32;
  int tx = threadIdx.x & 31, ty = threadIdx.x >> 5;
#pragma unroll
  for (int i = 0; i < 4; ++i) {
    int k = ty + i * 8;
    f32x2 p = ((const f32x2*)(W + (size_t)(kb + k) * 1536))[nb + tx];
    tile[k][tx] = p.x - p.y;
  }
  __syncthreads();
#pragma unroll
  for (int i = 0; i < 4; ++i) {
    int n = ty + i * 8;
    float d = tile[tx][n];
    __hip_bfloat16 h1 = __float2bfloat16(d);
    float r1 = d - __bfloat162float(h1);
    __hip_bfloat16 h2 = __float2bfloat16(r1);
    float r2 = r1 - __bfloat162float(h2);
    __hip_bfloat16 h3 = __float2bfloat16(r2);
    size_t base = (size_t)(nb + n) * 2304 + kb + tx;
    out[base] = h1; out[base + 768] = h2; out[base + 1536] = h3;
  }
}

// ---------- feat -> FS [BT, 2304] bf16 3-split, 4 elems/thread
__global__ void featsplit_kernel(const float* __restrict__ fv, const float* __restrict__ fi,
                                 __hip_bfloat16* __restrict__ FS) {
  int idx4 = blockIdx.x * 256 + threadIdx.x;  // BT*192
  int m = idx4 / 192, q = idx4 - m * 192;
  int c0 = q * 4;
  f32x4 f;
  if (c0 < 512) f = *(const f32x4*)(fv + (size_t)m * 512 + c0);
  else          f = *(const f32x4*)(fi + (size_t)m * 256 + (c0 - 512));
  unsigned short h1[4], h2[4], h3[4];
#pragma unroll
  for (int j = 0; j < 4; ++j) {
    float x = f[j];
    __hip_bfloat16 a = __float2bfloat16(x);
    float r1 = x - __bfloat162float(a);
    __hip_bfloat16 b = __float2bfloat16(r1);
    float r2 = r1 - __bfloat162float(b);
    __hip_bfloat16 c = __float2bfloat16(r2);
    h1[j] = *(unsigned short*)&a; h2[j] = *(unsigned short*)&b; h3[j] = *(unsigned short*)&c;
  }
  size_t base = (size_t)m * 2304 + c0;
  *(ushort4*)((unsigned short*)FS + base)        = make_ushort4(h1[0], h1[1], h1[2], h1[3]);
  *(ushort4*)((unsigned short*)FS + base + 768)  = make_ushort4(h2[0], h2[1], h2[2], h2[3]);
  *(ushort4*)((unsigned short*)FS + base + 1536) = make_ushort4(h3[0], h3[1], h3[2], h3[3]);
}

// ---------- fused LN + time-mix: 5 waves, 4 tokens/block + halo
__global__ void lnmix3_kernel(const float* __restrict__ X, const float* __restrict__ g,
                              const float* __restrict__ b, const float* __restrict__ mk,
                              const float* __restrict__ mv, const float* __restrict__ mr,
                              __hip_bfloat16* __restrict__ AK, __hip_bfloat16* __restrict__ AV,
                              __hip_bfloat16* __restrict__ AR) {
  __shared__ float xn[5][768];
  int tok0 = blockIdx.x * 4;
  int w = threadIdx.x >> 6, lane = threadIdx.x & 63;
  int t = tok0 + w - 1;
  if (t >= 0) {
    const float* row = X + (size_t)t * 768;
    float vv[12]; float s = 0.f, s2 = 0.f;
#pragma unroll
    for (int i = 0; i < 12; ++i) { float x = row[lane + i * 64]; vv[i] = x; s += x; s2 += x * x; }
#pragma unroll
    for (int o = 32; o; o >>= 1) { s += __shfl_xor(s, o); s2 += __shfl_xor(s2, o); }
    float m = s * (1.0f / 768.0f);
    float var = s2 * (1.0f / 768.0f) - m * m;
    float inv = 1.0f / sqrtf(var + 1e-5f);
#pragma unroll
    for (int i = 0; i < 12; ++i) { int c = lane + i * 64; xn[w][c] = (vv[i] - m) * inv * g[c] + b[c]; }
  }
  __syncthreads();
  if (w >= 1) {
    int tt = tok0 + (w - 1);
    bool first = (tt & 511) == 0;
    size_t base = (size_t)tt * 768;
#pragma unroll
    for (int i = 0; i < 12; ++i) {
      int c = lane + i * 64;
      float a = xn[w][c];
      float sft = first ? 0.0f : xn[w - 1][c];
      float k = mk[c], v = mv[c], r = mr[c];
      AK[base + c] = __float2bfloat16(a * k + sft * (1.0f - k));
      AV[base + c] = __float2bfloat16(a * v + sft * (1.0f - v));
      AR[base + c] = __float2bfloat16(a * r + sft * (1.0f - r));
    }
  }
}

__global__ void lnmix2_kernel(const float* __restrict__ X, const float* __restrict__ g,
                              const float* __restrict__ b, const float* __restrict__ mk,
                              const float* __restrict__ mr,
                              __hip_bfloat16* __restrict__ AK, __hip_bfloat16* __restrict__ AR) {
  __shared__ float xn[5][768];
  int tok0 = blockIdx.x * 4;
  int w = threadIdx.x >> 6, lane = threadIdx.x & 63;
  int t = tok0 + w - 1;
  if (t >= 0) {
    const float* row = X + (size_t)t * 768;
    float vv[12]; float s = 0.f, s2 = 0.f;
#pragma unroll
    for (int i = 0; i < 12; ++i) { float x = row[lane + i * 64]; vv[i] = x; s += x; s2 += x * x; }
#pragma unroll
    for (int o = 32; o; o >>= 1) { s += __shfl_xor(s, o); s2 += __shfl_xor(s2, o); }
    float m = s * (1.0f / 768.0f);
    float var = s2 * (1.0f / 768.0f) - m * m;
    float inv = 1.0f / sqrtf(var + 1e-5f);
#pragma unroll
    for (int i = 0; i < 12; ++i) { int c = lane + i * 64; xn[w][c] = (vv[i] - m) * inv * g[c] + b[c]; }
  }
  __syncthreads();
  if (w >= 1) {
    int tt = tok0 + (w - 1);
    bool first = (tt & 511) == 0;
    size_t base = (size_t)tt * 768;
#pragma unroll
    for (int i = 0; i < 12; ++i) {
      int c = lane + i * 64;
      float a = xn[w][c];
      float sft = first ? 0.0f : xn[w - 1][c];
      float k = mk[c], r = mr[c];
      AK[base + c] = __float2bfloat16(a * k + sft * (1.0f - k));
      AR[base + c] = __float2bfloat16(a * r + sft * (1.0f - r));
    }
  }
}

// ---------- WKV scan: one thread per (b,c), group-of-4 software pipeline
__global__ void wkv_kernel(const float* __restrict__ K, const float* __restrict__ V,
                           const float* __restrict__ RP, const float* __restrict__ td,
                           const float* __restrict__ tfirst, __hip_bfloat16* __restrict__ RA) {
  int idx = blockIdx.x * 256 + threadIdx.x;  // 32*768
  int b = idx / 768, c = idx - b * 768;
  float decay = -__expf(td[c]);
  float u = tfirst[c];
  float aa = 0.f, bb = 0.f, pp = -1e38f;
  size_t o = (size_t)b * 512 * 768 + c;
  float ck[4], cv[4], cr[4], nk[4], nv[4], nr[4];
#pragma unroll
  for (int j = 0; j < 4; ++j) { size_t oj = o + (size_t)j * 768; ck[j] = K[oj]; cv[j] = V[oj]; cr[j] = RP[oj]; }
  size_t ob = o;
  for (int g = 0; g < 128; ++g) {
    size_t onext = (g == 127) ? o : ob + 3072;
#pragma unroll
    for (int j = 0; j < 4; ++j) {
      size_t oj = onext + (size_t)j * 768;
      nk[j] = K[oj]; nv[j] = V[oj]; nr[j] = RP[oj];
    }
#pragma unroll
    for (int j = 0; j < 4; ++j) {
      float kt = ck[j], vt = cv[j];
      float ww = u + kt;
      float p = fmaxf(pp, ww);
      float e1 = __expf(pp - p), e2 = __expf(ww - p);
      float wkv = (e1 * aa + e2 * vt) / (e1 * bb + e2);
      float ww2 = pp + decay;
      float p2 = fmaxf(ww2, kt);
      float f1 = __expf(ww2 - p2), f2 = __expf(kt - p2);
      aa = f1 * aa + f2 * vt; bb = f1 * bb + f2; pp = p2;
      float r = 1.0f / (1.0f + __expf(-cr[j]));
      RA[ob + (size_t)j * 768] = __float2bfloat16(r * wkv);
    }
#pragma unroll
    for (int j = 0; j < 4; ++j) { ck[j] = nk[j]; cv[j] = nv[j]; cr[j] = nr[j]; }
    ob += 3072;
  }
}

// ---------- regressor stage 2
__global__ void reg2_kernel(const __hip_bfloat16* __restrict__ Hb, const float* __restrict__ W2,
                            const float* __restrict__ b2, float* __restrict__ out) {
  __shared__ float w[768];
  for (int i = threadIdx.x; i < 768; i += 256) w[i] = W2[i];
  __syncthreads();
  int m = blockIdx.x * 256 + threadIdx.x;
  float acc[6];
#pragma unroll
  for (int j = 0; j < 6; ++j) acc[j] = b2[j];
  const bf16x8* hr8 = (const bf16x8*)(Hb + (size_t)m * 128);
#pragma unroll
  for (int h8 = 0; h8 < 16; ++h8) {
    bf16x8 pk = hr8[h8];
#pragma unroll
    for (int e = 0; e < 8; ++e) {
      float hv = b2f((unsigned short)pk[e]);
      int h = h8 * 8 + e;
#pragma unroll
      for (int j = 0; j < 6; ++j) acc[j] += hv * w[h * 6 + j];
    }
  }
#pragma unroll
  for (int j = 0; j < 6; ++j) out[(size_t)m * 6 + j] = acc[j];
}

// ---------- MFMA GEMM: A [M,Kphys] bf16 rm, Bt [N,Kphys] bf16 rm. 128x128 tile, BK=64.
// R2 skeleton (single 32KB LDS buffer, 2 barriers/K-step) + in-register tile
// prefetch: per step, ds_read the WHOLE tile to registers first, barrier, then
// issue next tile's global_load_lds into the same buffer, then MFMA on regs
// (load latency hides under MFMA), barrier (drain). No vm-alias hazard: no
// ds_read ever follows an outstanding global_load_lds within a step.
enum { EP_NONE = 0, EP_GATE, EP_RESID, EP_RELUSQ, EP_SIGRESID, EP_LEAKY };

template<int EP, bool SPLIT6>
__global__ __launch_bounds__(256, 3) void gemm_bt(
                        const __hip_bfloat16* __restrict__ A, const __hip_bfloat16* __restrict__ Bt,
                        int N, int Kphys, int Klog,
                        size_t aZ, size_t bZ, size_t oZ,
                        float* __restrict__ outF, __hip_bfloat16* __restrict__ outH,
                        const float* __restrict__ x0, const float* __restrict__ x1,
                        const float* __restrict__ x2, const float* __restrict__ x3) {
  __shared__ __align__(16) unsigned short sA[8192];
  __shared__ __align__(16) unsigned short sB[8192];
  const int tid = threadIdx.x;
  const int lane = tid & 63;
  const int wid = tid >> 6;
  const int tm = blockIdx.x * 128, tn = blockIdx.y * 128;
  const int wr = (wid >> 1) * 64, wc = (wid & 1) * 64;
  const int r16 = lane & 15, kg = lane >> 4;
  const int z = blockIdx.z;
  A += (size_t)z * aZ; Bt += (size_t)z * bZ;

  f32x4 acc[4][4];
  f32x4 zero = {0.f, 0.f, 0.f, 0.f};
#pragma unroll
  for (int i = 0; i < 4; ++i)
#pragma unroll
    for (int j = 0; j < 4; ++j) acc[i][j] = zero;

  // staging: 16 chunks of 1KB (8 rows x 64 k each); wave w issues chunks 4w..4w+3.
  // lane l in chunk c writes LDS row r=c*8+(l>>3), 16B-slot (l&7); global source
  // is 16B-slot (l&7)^(r&7) (inverse XOR pre-swizzle; read side applies XOR).
  unsigned gA[4], gB[4];
  int ldsOff[4];
#pragma unroll
  for (int i = 0; i < 4; ++i) {
    int c = (wid << 2) | i;
    int row = (c << 3) | (lane >> 3);
    int swz = ((lane & 7) ^ (row & 7)) << 3;  // element offset
    gA[i] = (unsigned)((tm + row) * Kphys + swz);
    gB[i] = (unsigned)((tn + row) * Kphys + swz);
    ldsOff[i] = c << 9;  // elements (1KB per chunk)
  }
  const int ca0 = ((kg ^ (r16 & 7)) << 4);
  const int ca1 = (((4 | kg) ^ (r16 & 7)) << 4);
  const int arow = (wr + r16) * 128;
  const int brow = (wc + r16) * 128;

  auto STAGE = [&](int st) {
    int k0 = st * 64;
    int kA, kB2;
    if (SPLIT6) {
      static constexpr int mapA[6] = {0, 0, 0, 1, 1, 2};
      static constexpr int mapB[6] = {0, 1, 2, 0, 1, 0};
      int s = k0 / 768; int kr = k0 - s * 768;
      kA = mapA[s] * 768 + kr; kB2 = mapB[s] * 768 + kr;
    } else { kA = k0; kB2 = k0; }
#pragma unroll
    for (int i = 0; i < 4; ++i) GLOAD16(A + gA[i] + kA, sA + ldsOff[i]);
#pragma unroll
    for (int i = 0; i < 4; ++i) GLOAD16(Bt + gB[i] + kB2, sB + ldsOff[i]);
  };

  const int nsteps = Klog / 64;
  STAGE(0);
  __syncthreads();
  for (int st = 0; st < nsteps; ++st) {
    // (a) read whole tile into registers
    bf16x8 af[2][4], bfv[2][4];
#pragma unroll
    for (int ks = 0; ks < 2; ++ks) {
      const int ca = ks ? ca1 : ca0;
#pragma unroll
      for (int f = 0; f < 4; ++f) {
        af[ks][f]  = *(const bf16x8*)((const char*)sA + arow + f * 2048 + ca);
        bfv[ks][f] = *(const bf16x8*)((const char*)sB + brow + f * 2048 + ca);
      }
    }
    __syncthreads();               // all waves done reading LDS
    // (b) issue next tile's loads (overlaps the MFMAs below)
    if (st + 1 < nsteps) STAGE(st + 1);
    // (c) compute on registers
#pragma unroll
    for (int ks = 0; ks < 2; ++ks)
#pragma unroll
      for (int fm = 0; fm < 4; ++fm)
#pragma unroll
        for (int fn = 0; fn < 4; ++fn)
          acc[fm][fn] = __builtin_amdgcn_mfma_f32_16x16x32_bf16(af[ks][fm], bfv[ks][fn], acc[fm][fn], 0, 0, 0);
    __syncthreads();               // drains the staged loads (vmcnt 0)
  }

  // epilogue: C[row][col], col = lane&15, row = (lane>>4)*4 + j
  const int er0 = tm + wr + (lane >> 4) * 4;
  const int ec0 = tn + wc + (lane & 15);
#pragma unroll
  for (int fm = 0; fm < 4; ++fm) {
#pragma unroll
    for (int fn = 0; fn < 4; ++fn) {
#pragma unroll
      for (int j = 0; j < 4; ++j) {
        int row = er0 + fm * 16 + j;
        int col = ec0 + fn * 16;
        float v = acc[fm][fn][j];
        size_t o = (size_t)row * N + col;
        if (EP == EP_NONE) {
          outF[(size_t)z * oZ + o] = v;
        } else if (EP == EP_RESID) {
          outF[o] += v;
        } else if (EP == EP_GATE) {
          size_t gi = ((size_t)row * 768 + col) * 2;
          float gd = x0[gi] - x0[gi + 1];
          float bd = x3[2 * col] - x3[2 * col + 1];
          float s = v + bd + gd;
          float feat = (col < 512) ? x1[(size_t)row * 512 + col]
                                   : x2[(size_t)row * 256 + col - 512];
          outF[o] = (s >= 0.0f) ? feat : 0.0f;
        } else if (EP == EP_RELUSQ) {
          float r = v > 0.f ? v : 0.f;
          outH[o] = __float2bfloat16(r * r);
        } else if (EP == EP_SIGRESID) {
          float sg = 1.0f / (1.0f + __expf(-x0[o]));
          float xv = x1[o] + sg * v;
          outH[o] = __float2bfloat16(xv);
        } else if (EP == EP_LEAKY) {
          float h = v + x0[col];
          h = h > 0.f ? h : 0.1f * h;
          outH[o] = __float2bfloat16(h);
        }
      }
    }
  }
}

extern "C" void kernel_launch(void* const* d_in, const int* in_sizes, int n_in,
                              void* d_out, int out_size, void* d_ws, size_t ws_size,
                              hipStream_t stream) {
  const float* fv     = (const float*)d_in[0];
  const float* fi     = (const float*)d_in[1];
  const float* fuse_W = (const float*)d_in[2];
  const float* fuse_b = (const float*)d_in[3];
  const float* gumbel = (const float*)d_in[4];
  const float* ln1_g  = (const float*)d_in[5];
  const float* ln1_b  = (const float*)d_in[6];
  const float* mix_k  = (const float*)d_in[7];
  const float* mix_v  = (const float*)d_in[8];
  const float* mix_r  = (const float*)d_in[9];
  const float* td     = (const float*)d_in[10];
  const float* tfirst = (const float*)d_in[11];
  const float* Wk     = (const float*)d_in[12];
  const float* Wv     = (const float*)d_in[13];
  const float* Wr     = (const float*)d_in[14];
  const float* Wo     = (const float*)d_in[15];
  const float* ln2_g  = (const float*)d_in[16];
  const float* ln2_b  = (const float*)d_in[17];
  const float* cmk    = (const float*)d_in[18];
  const float* cmr    = (const float*)d_in[19];
  const float* cWk    = (const float*)d_in[20];
  const float* cWv    = (const float*)d_in[21];
  const float* cWr    = (const float*)d_in[22];
  const float* rW1    = (const float*)d_in[23];
  const float* rb1    = (const float*)d_in[24];
  const float* rW2    = (const float*)d_in[25];
  const float* rb2    = (const float*)d_in[26];

  char* ws = (char*)d_ws;
  float* X  = (float*)(ws + 0);
  float* Kb = (float*)(ws + 100663296UL);
  float* RP = (float*)(ws + 201326592UL);
  __hip_bfloat16* AK  = (__hip_bfloat16*)(ws + 251658240UL);
  __hip_bfloat16* AV  = (__hip_bfloat16*)(ws + 276824064UL);
  __hip_bfloat16* AR  = (__hip_bfloat16*)(ws + 301989888UL);
  __hip_bfloat16* RA  = (__hip_bfloat16*)(ws + 327155712UL);
  __hip_bfloat16* Hb  = (__hip_bfloat16*)(ws + 352321536UL);
  __hip_bfloat16* WdT = (__hip_bfloat16*)(ws + 356515840UL);
  __hip_bfloat16* WkT = (__hip_bfloat16*)(ws + 360054784UL);
  __hip_bfloat16* WvT = (__hip_bfloat16*)(ws + 361234432UL);
  __hip_bfloat16* WrT = (__hip_bfloat16*)(ws + 362414080UL);
  __hip_bfloat16* WoT = (__hip_bfloat16*)(ws + 363593728UL);
  __hip_bfloat16* cWkT = (__hip_bfloat16*)(ws + 364773376UL);
  __hip_bfloat16* cWvT = (__hip_bfloat16*)(ws + 369491968UL);
  __hip_bfloat16* cWrT = (__hip_bfloat16*)(ws + 374210560UL);
  __hip_bfloat16* W1T  = (__hip_bfloat16*)(ws + 375390208UL);
  // aliases over dead K/V region:
  __hip_bfloat16* FS = (__hip_bfloat16*)(ws + 100663296UL);  // [BT,2304], dead after gate
  __hip_bfloat16* KK = (__hip_bfloat16*)(ws + 100663296UL);  // [BT,3072], after Kb/Vb dead

  dim3 blk(256);

  // weight converts
  wconv5_kernel<<<dim3(24, 24, 5), blk, 0, stream>>>(Wk, Wv, Wr, Wo, cWr,
                                                     WkT, WvT, WrT, WoT, cWrT);
  wconv_kernel<<<dim3(24, 96), blk, 0, stream>>>(cWk, cWkT, 768, 3072);
  wconv_kernel<<<dim3(96, 24), blk, 0, stream>>>(cWv, cWvT, 3072, 768);
  wconv_kernel<<<dim3(24, 4),  blk, 0, stream>>>(rW1, W1T, 768, 128);
  wdsplit_kernel<<<dim3(24, 24), blk, 0, stream>>>(fuse_W, WdT);

  // fusion gate
  featsplit_kernel<<<12288, blk, 0, stream>>>(fv, fi, FS);
  gemm_bt<EP_GATE, true><<<dim3(128, 6, 1), blk, 0, stream>>>(
      FS, WdT, 768, 2304, 4608, 0, 0, 0, X, nullptr, gumbel, fv, fi, fuse_b);

  // RWKV time-mix
  lnmix3_kernel<<<4096, dim3(320), 0, stream>>>(X, ln1_g, ln1_b, mix_k, mix_v, mix_r, AK, AV, AR);
  gemm_bt<EP_NONE, false><<<dim3(128, 6, 3), blk, 0, stream>>>(
      AK, WkT, 768, 768, 768, 12582912UL, 589824UL, 12582912UL,
      Kb, nullptr, nullptr, nullptr, nullptr, nullptr);
  wkv_kernel<<<96, blk, 0, stream>>>(Kb, Kb + 12582912UL, RP, td, tfirst, RA);
  gemm_bt<EP_RESID, false><<<dim3(128, 6, 1), blk, 0, stream>>>(
      RA, WoT, 768, 768, 768, 0, 0, 0, X, nullptr, nullptr, nullptr, nullptr, nullptr);

  // RWKV channel-mix
  lnmix2_kernel<<<4096, dim3(320), 0, stream>>>(X, ln2_g, ln2_b, cmk, cmr, AK, AR);
  gemm_bt<EP_RELUSQ, false><<<dim3(128, 24, 1), blk, 0, stream>>>(
      AK, cWkT, 3072, 768, 768, 0, 0, 0, nullptr, KK, nullptr, nullptr, nullptr, nullptr);
  gemm_bt<EP_NONE, false><<<dim3(128, 6, 1), blk, 0, stream>>>(
      AR, cWrT, 768, 768, 768, 0, 0, 0, RP, nullptr, nullptr, nullptr, nullptr, nullptr);
  gemm_bt<EP_SIGRESID, false><<<dim3(128, 6, 1), blk, 0, stream>>>(
      KK, cWvT, 768, 3072, 3072, 0, 0, 0, nullptr, AV, RP, X, nullptr, nullptr);

  // regressor (AV now holds bf16 of final x)
  gemm_bt<EP_LEAKY, false><<<dim3(128, 1, 1), blk, 0, stream>>>(
      AV, W1T, 128, 768, 768, 0, 0, 0, nullptr, Hb, rb1, nullptr, nullptr, nullptr);
  reg2_kernel<<<64, blk, 0, stream>>>(Hb, rW2, rb2, (float*)d_out);
}